// Round 1
// baseline (290.037 us; speedup 1.0000x reference)
//
#include <hip/hip_runtime.h>
#include <math.h>

#define TPB 256

// ---- LDS layout (float offsets), lifetime-overlaid. Weights in GLOBAL/L2. ----
// x  [0,784)        staged input; dead after dyn phase
// c1 [784,1752)     conv7 out; dead after conv5
// y  [784,2474)     dyn out (over c1); read by conv2
// f  [1752,1842)    conv5 out  (hole past c1, before y is written; dead pre-dyn)
// h  [1842,1874)    fc1 out    (same hole)
// k  [2474,2514)    dyn kernels — alive WHILE y is written, so past y's end
// P2 [2514,3814)    conv2 ic<5 half-partials [20][65] (h=1 half stays in regs)
// p3 [0,320) pf [320,570) a1 [570,620) z [620,630)   (all over dead x)
#define OX    0
#define OC1   784
#define OY    784
#define OF    1752
#define OH    1842
#define OK2   2474
#define OP2   2514
#define OP3   0
#define OPF   320
#define OA1   570
#define OZ    620
#define SM_TOT 3814   // 15256 B -> LDS allows 10 blk/CU; wave cap gives 8 blk/CU

// NOTE: no min-waves launch bound — R3 showed (256,5) forces VGPR=48 + scratch
// spill (WRITE_SIZE 0.5->237 MB). VGPR must stay <=64 for 8 waves/SIMD.
// Lane maps keep oc in LOW lane bits: same-address lanes broadcast (free);
// R5->R6 cut SQ_LDS_BANK_CONFLICT 2.3e7 -> 3.9e6 this way.
__global__ __launch_bounds__(TPB) void fused_forward(
    const float* __restrict__ x,
    const float* __restrict__ kf_w1, const float* __restrict__ kf_b1,
    const float* __restrict__ kf_w2, const float* __restrict__ kf_b2,
    const float* __restrict__ kf_fc1_w, const float* __restrict__ kf_fc1_b,
    const float* __restrict__ kf_fc2_w, const float* __restrict__ kf_fc2_b,
    const float* __restrict__ conv2_w, const float* __restrict__ conv2_b,
    const float* __restrict__ fc1_w, const float* __restrict__ fc1_b,
    const float* __restrict__ fc2_w, const float* __restrict__ fc2_b,
    float* __restrict__ out)
{
    __shared__ float sm[SM_TOT];
    const int tid = threadIdx.x;
    const int n = blockIdx.x;

    // ---- stage 0: stage x into LDS (float4) ----
    {
        const float4* xg = (const float4*)(x + (long long)n * 784);
        float4* d = (float4*)&sm[OX];
        for (int i = tid; i < 196; i += TPB) d[i] = xg[i];
    }
    __syncthreads();

    // ---- conv7 (28->22) + pool (->11) + relu ----
    // lane map: oc = tid&7 -> 8-lane broadcast of every x address.
    if (tid < 176) {
        int oc = tid & 7;
        int r  = tid >> 3;
        int py = r >> 1;
        int h  = r & 1;
        int cc0 = 10 * h;
        float c[2][12];
        #pragma unroll
        for (int r2 = 0; r2 < 2; ++r2)
            #pragma unroll
            for (int i = 0; i < 12; ++i) c[r2][i] = 0.f;
        float wc[7], wp[7];
        const float* wg = kf_w1 + oc * 49;
        #pragma unroll
        for (int i = 0; i < 7; ++i) wc[i] = wg[i];
        #pragma unroll
        for (int t = 0; t < 8; ++t) {
            const float* xs = &sm[OX + (2 * py + t) * 28 + cc0];
            float row[18];
            #pragma unroll
            for (int i = 0; i < 18; ++i) row[i] = xs[i];
            if (t <= 6) {
                #pragma unroll
                for (int kx = 0; kx < 7; ++kx)
                    #pragma unroll
                    for (int cc = 0; cc < 12; ++cc)
                        c[0][cc] = fmaf(wc[kx], row[cc + kx], c[0][cc]);
            }
            if (t >= 1) {
                #pragma unroll
                for (int kx = 0; kx < 7; ++kx)
                    #pragma unroll
                    for (int cc = 0; cc < 12; ++cc)
                        c[1][cc] = fmaf(wp[kx], row[cc + kx], c[1][cc]);
            }
            #pragma unroll
            for (int i = 0; i < 7; ++i) wp[i] = wc[i];
            if (t < 7) {
                const float* wn = wg + (t + 1) * 7;
                #pragma unroll
                for (int i = 0; i < 7; ++i) wc[i] = wn[i];
            }
        }
        float b = kf_b1[oc];
        #pragma unroll
        for (int j = 0; j < 6; ++j) {
            float m = fmaxf(fmaxf(c[0][2 * j], c[0][2 * j + 1]),
                            fmaxf(c[1][2 * j], c[1][2 * j + 1]));
            sm[OC1 + oc * 121 + py * 11 + 5 * h + j] = fmaxf(m + b, 0.f);
        }
    }
    __syncthreads();

    // ---- conv5 (11->7) + pool (->3) + relu: full-depth, no partials ----
    // thread = (py,px,oc), oc = tid%10 -> 10-lane broadcast; 90 threads x 800 FMA.
    if (tid < 90) {
        int oc = tid % 10, r = tid / 10;
        int py = r / 3, px = r % 3;
        float a00 = 0.f, a01 = 0.f, a10 = 0.f, a11 = 0.f;
        for (int ic = 0; ic < 8; ++ic) {
            float w[25];
            const float* wg = kf_w2 + (oc * 8 + ic) * 25;
            #pragma unroll
            for (int i = 0; i < 25; ++i) w[i] = wg[i];
            const float* xb = &sm[OC1 + ic * 121 + 2 * py * 11 + 2 * px];
            float cur[6], nxt[6];
            #pragma unroll
            for (int i = 0; i < 6; ++i) cur[i] = xb[i];
            #pragma unroll
            for (int ky = 0; ky < 5; ++ky) {
                const float* xr = xb + (ky + 1) * 11;
                #pragma unroll
                for (int i = 0; i < 6; ++i) nxt[i] = xr[i];
                #pragma unroll
                for (int kx = 0; kx < 5; ++kx) {
                    float wv = w[ky * 5 + kx];
                    a00 = fmaf(wv, cur[kx],     a00);
                    a01 = fmaf(wv, cur[kx + 1], a01);
                    a10 = fmaf(wv, nxt[kx],     a10);
                    a11 = fmaf(wv, nxt[kx + 1], a11);
                }
                #pragma unroll
                for (int i = 0; i < 6; ++i) cur[i] = nxt[i];
            }
        }
        float m = fmaxf(fmaxf(a00, a01), fmaxf(a10, a11)) + kf_b2[oc];
        sm[OF + oc * 9 + py * 3 + px] = fmaxf(m, 0.f);
    }
    __syncthreads();

    // ---- fc 90->32 + relu, then fc 32->40: both wave 0, no barrier between
    // (intra-wave LDS ops are in-order; h written+read by the same wave).
    if (tid < 32) {
        float acc = kf_fc1_b[tid];
        const float* wr = &kf_fc1_w[tid * 90];
        for (int i = 0; i < 90; ++i) acc = fmaf(wr[i], sm[OF + i], acc);
        sm[OH + tid] = fmaxf(acc, 0.f);
    }
    if (tid < 40) {
        float acc = kf_fc2_b[tid];
        const float* wr = &kf_fc2_w[tid * 32];
        #pragma unroll
        for (int i = 0; i < 32; ++i) acc = fmaf(wr[i], sm[OH + i], acc);
        sm[OK2 + tid] = acc;
    }
    __syncthreads();

    // ---- dynamic 2x2 conv + pool + relu; oc = tid%10 broadcast map ----
    if (tid < 130) {
        int oc = tid % 10, py = tid / 10;
        float k0 = sm[OK2 + oc * 4 + 0], k1 = sm[OK2 + oc * 4 + 1];
        float k2 = sm[OK2 + oc * 4 + 2], k3 = sm[OK2 + oc * 4 + 3];
        const float* x0 = &sm[OX + 2 * py * 28];
        const float* x1 = x0 + 28;
        const float* x2 = x0 + 56;
        float A0 = x0[0], A1 = x1[0], A2 = x2[0];
        float B0 = x0[1], B1 = x1[1], B2 = x2[1];
        #pragma unroll
        for (int j = 0; j < 13; ++j) {
            float C0 = x0[2 * j + 2], C1 = x1[2 * j + 2], C2 = x2[2 * j + 2];
            float c00 = A0 * k0 + B0 * k1 + A1 * k2 + B1 * k3;
            float c01 = B0 * k0 + C0 * k1 + B1 * k2 + C1 * k3;
            float c10 = A1 * k0 + B1 * k1 + A2 * k2 + B2 * k3;
            float c11 = B1 * k0 + C1 * k1 + B2 * k2 + C2 * k3;
            float m = fmaxf(fmaxf(c00, c01), fmaxf(c10, c11));
            sm[OY + oc * 169 + py * 13 + j] = fmaxf(m, 0.f);
            A0 = C0; A1 = C1; A2 = C2;
            if (j < 12) { B0 = x0[2 * j + 3]; B1 = x1[2 * j + 3]; B2 = x2[2 * j + 3]; }
        }
    }
    __syncthreads();

    // ---- conv2 5x5: ONLY the 8x8 outputs the pool reads (row/col 8 discarded)
    // thread = (h2, rg4, oc20), oc = tid%20 broadcast; 2x8 tile, 5 ic each.
    // h2=0 half writes partials to P2 [20][65] (pad 65 -> conflict-free);
    // h2=1 half KEEPS acc[2][8] in registers across the barrier and combines.
    const int oc2 = tid % 20;
    const int q2  = tid / 20;          // 0..7 for active threads
    const int h2  = q2 & 1;
    const int rg2 = q2 >> 1;           // 0..3
    float a2[2][8];
    if (tid < 160) {
        int r0 = 2 * rg2;              // output rows r0, r0+1
        #pragma unroll
        for (int r = 0; r < 2; ++r)
            #pragma unroll
            for (int i = 0; i < 8; ++i) a2[r][i] = 0.f;
        for (int icg = 0; icg < 5; ++icg) {
            int ic = 5 * h2 + icg;
            float w[25];
            const float* wg = conv2_w + (oc2 * 10 + ic) * 25;
            #pragma unroll
            for (int i = 0; i < 25; ++i) w[i] = wg[i];
            const float* yb = &sm[OY + ic * 169 + r0 * 13];
            #pragma unroll
            for (int u = 0; u < 6; ++u) {
                const float* ys = yb + u * 13;
                float row[12];
                #pragma unroll
                for (int i = 0; i < 12; ++i) row[i] = ys[i];
                #pragma unroll
                for (int rr = 0; rr < 2; ++rr) {
                    int ky = u - rr;
                    if (ky >= 0 && ky <= 4) {
                        #pragma unroll
                        for (int kx = 0; kx < 5; ++kx)
                            #pragma unroll
                            for (int cx = 0; cx < 8; ++cx)
                                a2[rr][cx] = fmaf(w[ky * 5 + kx], row[cx + kx], a2[rr][cx]);
                    }
                }
            }
        }
        if (h2 == 0) {
            int r0w = 2 * rg2;
            #pragma unroll
            for (int rr = 0; rr < 2; ++rr)
                #pragma unroll
                for (int cx = 0; cx < 8; ++cx)
                    sm[OP2 + oc2 * 65 + (r0w + rr) * 8 + cx] = a2[rr][cx];
        }
    }
    __syncthreads();

    // ---- combine halves + bias + pool + relu -> p3[20,4,4] (80 h2=1 threads,
    // ic>=5 partials still live in their registers; ic<5 read from P2) ----
    if (tid < 160 && h2 == 1) {
        float b = conv2_b[oc2];
        const float* p0 = &sm[OP2 + oc2 * 65 + (2 * rg2) * 8];
        #pragma unroll
        for (int px = 0; px < 4; ++px) {
            float c00 = b + a2[0][2 * px]     + p0[2 * px];
            float c01 = b + a2[0][2 * px + 1] + p0[2 * px + 1];
            float c10 = b + a2[1][2 * px]     + p0[8 + 2 * px];
            float c11 = b + a2[1][2 * px + 1] + p0[8 + 2 * px + 1];
            float m = fmaxf(fmaxf(c00, c01), fmaxf(c10, c11));
            sm[OP3 + oc2 * 16 + rg2 * 4 + px] = fmaxf(m, 0.f);
        }
    }
    __syncthreads();

    // ---- fc 320->50, 5-way k-split ----
    if (tid < 250) {
        int g = tid / 50, o = tid % 50;
        const float* wr = &fc1_w[o * 320 + g * 64];
        const float* pp = &sm[OP3 + g * 64];
        float acc = 0.f;
        #pragma unroll
        for (int i = 0; i < 64; ++i) acc = fmaf(wr[i], pp[i], acc);
        sm[OPF + tid] = acc;
    }
    __syncthreads();

    // ---- tail: all wave 0, barrier-free (intra-wave LDS ordering) ----
    if (tid < 50) {
        float acc = fc1_b[tid];
        #pragma unroll
        for (int g = 0; g < 5; ++g) acc += sm[OPF + g * 50 + tid];
        sm[OA1 + tid] = fmaxf(acc, 0.f);
    }
    if (tid < 10) {
        float acc = fc2_b[tid];
        const float* wr = &fc2_w[tid * 50];
        #pragma unroll
        for (int i = 0; i < 50; ++i) acc = fmaf(wr[i], sm[OA1 + i], acc);
        sm[OZ + tid] = acc;
    }
    if (tid < 10) {
        float m = sm[OZ + 0];
        #pragma unroll
        for (int i = 1; i < 10; ++i) m = fmaxf(m, sm[OZ + i]);
        float s = 0.f;
        #pragma unroll
        for (int i = 0; i < 10; ++i) s += expf(sm[OZ + i] - m);
        out[n * 10 + tid] = sm[OZ + tid] - m - logf(s);
    }
}

extern "C" void kernel_launch(void* const* d_in, const int* in_sizes, int n_in,
                              void* d_out, int out_size, void* d_ws, size_t ws_size,
                              hipStream_t stream) {
    const float* x        = (const float*)d_in[0];
    const float* kf_w1    = (const float*)d_in[1];
    const float* kf_b1    = (const float*)d_in[2];
    const float* kf_w2    = (const float*)d_in[3];
    const float* kf_b2    = (const float*)d_in[4];
    const float* kf_fc1_w = (const float*)d_in[5];
    const float* kf_fc1_b = (const float*)d_in[6];
    const float* kf_fc2_w = (const float*)d_in[7];
    const float* kf_fc2_b = (const float*)d_in[8];
    const float* conv2_w  = (const float*)d_in[9];
    const float* conv2_b  = (const float*)d_in[10];
    const float* fc1_w    = (const float*)d_in[11];
    const float* fc1_b    = (const float*)d_in[12];
    const float* fc2_w    = (const float*)d_in[13];
    const float* fc2_b    = (const float*)d_in[14];

    const int N = in_sizes[0] / 784;   // 8192

    fused_forward<<<N, TPB, 0, stream>>>(
        x, kf_w1, kf_b1, kf_w2, kf_b2, kf_fc1_w, kf_fc1_b, kf_fc2_w, kf_fc2_b,
        conv2_w, conv2_b, fc1_w, fc1_b, fc2_w, fc2_b, (float*)d_out);
}

// Round 2
// 287.874 us; speedup vs baseline: 1.0075x; 1.0075x over previous
//
#include <hip/hip_runtime.h>
#include <math.h>

#define TPB 192

// ---- LDS layout (float offsets), lifetime-overlaid. Weights in GLOBAL/L2. ----
// x  [0,784)        staged input; dead after dyn phase
// c1 [784,1752)     conv7 out; dead after conv5
// y  [784,2474)     dyn out (over c1); read by conv2
// f  [1752,1842)    conv5 out  (hole past c1, before y is written; dead pre-dyn)
// h  [1842,1874)    fc1 out    (same hole)
// k  [2474,2514)    dyn kernels — alive WHILE y is written, so past y's end
// P2 [2514,3814)    conv2 ic<5 half-partials [20][65] (h=1 half stays in regs)
// p3 [0,321) pf [324,474) a1 [480,530) z [532,542)   (all over dead x)
// p3[320] is a zero pad so the 3-way fc1 k-split can use uniform len 107.
#define OX    0
#define OC1   784
#define OY    784
#define OF    1752
#define OH    1842
#define OK2   2474
#define OP2   2514
#define OP3   0
#define OPF   324
#define OA1   480
#define OZ    532
#define SM_TOT 3814   // 15256 B; blocks/CU = min(LDS 10, wavecap 32/3=10) = 10

// TPB=192 (R2): wave 3 of the 256-thread version was dead weight — ~70 useful
// instrs all kernel (only stage-x remainder + 58 lanes of fc320). 3-wave
// blocks put every resident wave on real phase work; 10 blocks/CU.
// Lane maps keep oc in LOW lane bits: same-address lanes broadcast (free).
__global__ __launch_bounds__(TPB) void fused_forward(
    const float* __restrict__ x,
    const float* __restrict__ kf_w1, const float* __restrict__ kf_b1,
    const float* __restrict__ kf_w2, const float* __restrict__ kf_b2,
    const float* __restrict__ kf_fc1_w, const float* __restrict__ kf_fc1_b,
    const float* __restrict__ kf_fc2_w, const float* __restrict__ kf_fc2_b,
    const float* __restrict__ conv2_w, const float* __restrict__ conv2_b,
    const float* __restrict__ fc1_w, const float* __restrict__ fc1_b,
    const float* __restrict__ fc2_w, const float* __restrict__ fc2_b,
    float* __restrict__ out)
{
    __shared__ float sm[SM_TOT];
    const int tid = threadIdx.x;
    const int n = blockIdx.x;

    // ---- stage 0: stage x into LDS (float4) ----
    {
        const float4* xg = (const float4*)(x + (long long)n * 784);
        float4* d = (float4*)&sm[OX];
        for (int i = tid; i < 196; i += TPB) d[i] = xg[i];
    }
    __syncthreads();

    // ---- conv7 (28->22) + pool (->11) + relu ----
    // lane map: oc = tid&7 -> 8-lane broadcast of every x address.
    if (tid < 176) {
        int oc = tid & 7;
        int r  = tid >> 3;
        int py = r >> 1;
        int h  = r & 1;
        int cc0 = 10 * h;
        float c[2][12];
        #pragma unroll
        for (int r2 = 0; r2 < 2; ++r2)
            #pragma unroll
            for (int i = 0; i < 12; ++i) c[r2][i] = 0.f;
        float wc[7], wp[7];
        const float* wg = kf_w1 + oc * 49;
        #pragma unroll
        for (int i = 0; i < 7; ++i) wc[i] = wg[i];
        #pragma unroll
        for (int t = 0; t < 8; ++t) {
            const float* xs = &sm[OX + (2 * py + t) * 28 + cc0];
            float row[18];
            #pragma unroll
            for (int i = 0; i < 18; ++i) row[i] = xs[i];
            if (t <= 6) {
                #pragma unroll
                for (int kx = 0; kx < 7; ++kx)
                    #pragma unroll
                    for (int cc = 0; cc < 12; ++cc)
                        c[0][cc] = fmaf(wc[kx], row[cc + kx], c[0][cc]);
            }
            if (t >= 1) {
                #pragma unroll
                for (int kx = 0; kx < 7; ++kx)
                    #pragma unroll
                    for (int cc = 0; cc < 12; ++cc)
                        c[1][cc] = fmaf(wp[kx], row[cc + kx], c[1][cc]);
            }
            #pragma unroll
            for (int i = 0; i < 7; ++i) wp[i] = wc[i];
            if (t < 7) {
                const float* wn = wg + (t + 1) * 7;
                #pragma unroll
                for (int i = 0; i < 7; ++i) wc[i] = wn[i];
            }
        }
        float b = kf_b1[oc];
        #pragma unroll
        for (int j = 0; j < 6; ++j) {
            float m = fmaxf(fmaxf(c[0][2 * j], c[0][2 * j + 1]),
                            fmaxf(c[1][2 * j], c[1][2 * j + 1]));
            sm[OC1 + oc * 121 + py * 11 + 5 * h + j] = fmaxf(m + b, 0.f);
        }
    }
    __syncthreads();

    // ---- conv5 (11->7) + pool (->3) + relu: full-depth, no partials ----
    // thread = (py,px,oc), oc = tid%10 -> 10-lane broadcast; 90 threads x 800 FMA.
    if (tid < 90) {
        int oc = tid % 10, r = tid / 10;
        int py = r / 3, px = r % 3;
        float a00 = 0.f, a01 = 0.f, a10 = 0.f, a11 = 0.f;
        for (int ic = 0; ic < 8; ++ic) {
            float w[25];
            const float* wg = kf_w2 + (oc * 8 + ic) * 25;
            #pragma unroll
            for (int i = 0; i < 25; ++i) w[i] = wg[i];
            const float* xb = &sm[OC1 + ic * 121 + 2 * py * 11 + 2 * px];
            float cur[6], nxt[6];
            #pragma unroll
            for (int i = 0; i < 6; ++i) cur[i] = xb[i];
            #pragma unroll
            for (int ky = 0; ky < 5; ++ky) {
                const float* xr = xb + (ky + 1) * 11;
                #pragma unroll
                for (int i = 0; i < 6; ++i) nxt[i] = xr[i];
                #pragma unroll
                for (int kx = 0; kx < 5; ++kx) {
                    float wv = w[ky * 5 + kx];
                    a00 = fmaf(wv, cur[kx],     a00);
                    a01 = fmaf(wv, cur[kx + 1], a01);
                    a10 = fmaf(wv, nxt[kx],     a10);
                    a11 = fmaf(wv, nxt[kx + 1], a11);
                }
                #pragma unroll
                for (int i = 0; i < 6; ++i) cur[i] = nxt[i];
            }
        }
        float m = fmaxf(fmaxf(a00, a01), fmaxf(a10, a11)) + kf_b2[oc];
        sm[OF + oc * 9 + py * 3 + px] = fmaxf(m, 0.f);
    }
    __syncthreads();

    // ---- fc 90->32 + relu, then fc 32->40: both wave 0, no barrier between
    // (intra-wave LDS ops are in-order; h written+read by the same wave).
    if (tid < 32) {
        float acc = kf_fc1_b[tid];
        const float* wr = &kf_fc1_w[tid * 90];
        for (int i = 0; i < 90; ++i) acc = fmaf(wr[i], sm[OF + i], acc);
        sm[OH + tid] = fmaxf(acc, 0.f);
    }
    if (tid < 40) {
        float acc = kf_fc2_b[tid];
        const float* wr = &kf_fc2_w[tid * 32];
        #pragma unroll
        for (int i = 0; i < 32; ++i) acc = fmaf(wr[i], sm[OH + i], acc);
        sm[OK2 + tid] = acc;
    }
    __syncthreads();

    // ---- dynamic 2x2 conv + pool + relu; oc = tid%10 broadcast map ----
    if (tid < 130) {
        int oc = tid % 10, py = tid / 10;
        float k0 = sm[OK2 + oc * 4 + 0], k1 = sm[OK2 + oc * 4 + 1];
        float k2 = sm[OK2 + oc * 4 + 2], k3 = sm[OK2 + oc * 4 + 3];
        const float* x0 = &sm[OX + 2 * py * 28];
        const float* x1 = x0 + 28;
        const float* x2 = x0 + 56;
        float A0 = x0[0], A1 = x1[0], A2 = x2[0];
        float B0 = x0[1], B1 = x1[1], B2 = x2[1];
        #pragma unroll
        for (int j = 0; j < 13; ++j) {
            float C0 = x0[2 * j + 2], C1 = x1[2 * j + 2], C2 = x2[2 * j + 2];
            float c00 = A0 * k0 + B0 * k1 + A1 * k2 + B1 * k3;
            float c01 = B0 * k0 + C0 * k1 + B1 * k2 + C1 * k3;
            float c10 = A1 * k0 + B1 * k1 + A2 * k2 + B2 * k3;
            float c11 = B1 * k0 + C1 * k1 + B2 * k2 + C2 * k3;
            float m = fmaxf(fmaxf(c00, c01), fmaxf(c10, c11));
            sm[OY + oc * 169 + py * 13 + j] = fmaxf(m, 0.f);
            A0 = C0; A1 = C1; A2 = C2;
            if (j < 12) { B0 = x0[2 * j + 3]; B1 = x1[2 * j + 3]; B2 = x2[2 * j + 3]; }
        }
    }
    __syncthreads();

    // ---- conv2 5x5: ONLY the 8x8 outputs the pool reads (row/col 8 discarded)
    // thread = (h2, rg4, oc20), oc = tid%20 broadcast; 2x8 tile, 5 ic each.
    // h2=0 half writes partials to P2 [20][65] (pad 65 -> conflict-free);
    // h2=1 half KEEPS acc[2][8] in registers across the barrier and combines.
    const int oc2 = tid % 20;
    const int q2  = tid / 20;          // 0..7 for active threads
    const int h2  = q2 & 1;
    const int rg2 = q2 >> 1;           // 0..3
    float a2[2][8];
    if (tid < 160) {
        int r0 = 2 * rg2;              // output rows r0, r0+1
        #pragma unroll
        for (int r = 0; r < 2; ++r)
            #pragma unroll
            for (int i = 0; i < 8; ++i) a2[r][i] = 0.f;
        for (int icg = 0; icg < 5; ++icg) {
            int ic = 5 * h2 + icg;
            float w[25];
            const float* wg = conv2_w + (oc2 * 10 + ic) * 25;
            #pragma unroll
            for (int i = 0; i < 25; ++i) w[i] = wg[i];
            const float* yb = &sm[OY + ic * 169 + r0 * 13];
            #pragma unroll
            for (int u = 0; u < 6; ++u) {
                const float* ys = yb + u * 13;
                float row[12];
                #pragma unroll
                for (int i = 0; i < 12; ++i) row[i] = ys[i];
                #pragma unroll
                for (int rr = 0; rr < 2; ++rr) {
                    int ky = u - rr;
                    if (ky >= 0 && ky <= 4) {
                        #pragma unroll
                        for (int kx = 0; kx < 5; ++kx)
                            #pragma unroll
                            for (int cx = 0; cx < 8; ++cx)
                                a2[rr][cx] = fmaf(w[ky * 5 + kx], row[cx + kx], a2[rr][cx]);
                    }
                }
            }
        }
        if (h2 == 0) {
            int r0w = 2 * rg2;
            #pragma unroll
            for (int rr = 0; rr < 2; ++rr)
                #pragma unroll
                for (int cx = 0; cx < 8; ++cx)
                    sm[OP2 + oc2 * 65 + (r0w + rr) * 8 + cx] = a2[rr][cx];
        }
    }
    __syncthreads();

    // ---- combine halves + bias + pool + relu -> p3[20,4,4] (80 h2=1 threads,
    // ic>=5 partials still live in their registers; ic<5 read from P2) ----
    if (tid < 160 && h2 == 1) {
        float b = conv2_b[oc2];
        const float* p0 = &sm[OP2 + oc2 * 65 + (2 * rg2) * 8];
        #pragma unroll
        for (int px = 0; px < 4; ++px) {
            float c00 = b + a2[0][2 * px]     + p0[2 * px];
            float c01 = b + a2[0][2 * px + 1] + p0[2 * px + 1];
            float c10 = b + a2[1][2 * px]     + p0[8 + 2 * px];
            float c11 = b + a2[1][2 * px + 1] + p0[8 + 2 * px + 1];
            float m = fmaxf(fmaxf(c00, c01), fmaxf(c10, c11));
            sm[OP3 + oc2 * 16 + rg2 * 4 + px] = fmaxf(m, 0.f);
        }
    }
    if (tid == 0) sm[OP3 + 320] = 0.f;   // pad so fc1 k-split can be uniform 107
    __syncthreads();

    // ---- fc 320->50, 3-way k-split (150 threads; 107+107+107 with zero pad) ----
    if (tid < 150) {
        int g = tid / 50, o = tid % 50;
        int k0 = g * 107;
        const float* wr = &fc1_w[o * 320];
        float acc = 0.f;
        if (g < 2) {
            for (int i = 0; i < 107; ++i)
                acc = fmaf(wr[k0 + i], sm[OP3 + k0 + i], acc);
        } else {
            for (int i = 0; i < 106; ++i)
                acc = fmaf(wr[k0 + i], sm[OP3 + k0 + i], acc);
        }
        sm[OPF + tid] = acc;
    }
    __syncthreads();

    // ---- tail: all wave 0, barrier-free (intra-wave LDS ordering) ----
    if (tid < 50) {
        float acc = fc1_b[tid];
        #pragma unroll
        for (int g = 0; g < 3; ++g) acc += sm[OPF + g * 50 + tid];
        sm[OA1 + tid] = fmaxf(acc, 0.f);
    }
    if (tid < 10) {
        float acc = fc2_b[tid];
        const float* wr = &fc2_w[tid * 50];
        #pragma unroll
        for (int i = 0; i < 50; ++i) acc = fmaf(wr[i], sm[OA1 + i], acc);
        sm[OZ + tid] = acc;
    }
    if (tid < 10) {
        float m = sm[OZ + 0];
        #pragma unroll
        for (int i = 1; i < 10; ++i) m = fmaxf(m, sm[OZ + i]);
        float s = 0.f;
        #pragma unroll
        for (int i = 0; i < 10; ++i) s += expf(sm[OZ + i] - m);
        out[n * 10 + tid] = sm[OZ + tid] - m - logf(s);
    }
}

extern "C" void kernel_launch(void* const* d_in, const int* in_sizes, int n_in,
                              void* d_out, int out_size, void* d_ws, size_t ws_size,
                              hipStream_t stream) {
    const float* x        = (const float*)d_in[0];
    const float* kf_w1    = (const float*)d_in[1];
    const float* kf_b1    = (const float*)d_in[2];
    const float* kf_w2    = (const float*)d_in[3];
    const float* kf_b2    = (const float*)d_in[4];
    const float* kf_fc1_w = (const float*)d_in[5];
    const float* kf_fc1_b = (const float*)d_in[6];
    const float* kf_fc2_w = (const float*)d_in[7];
    const float* kf_fc2_b = (const float*)d_in[8];
    const float* conv2_w  = (const float*)d_in[9];
    const float* conv2_b  = (const float*)d_in[10];
    const float* fc1_w    = (const float*)d_in[11];
    const float* fc1_b    = (const float*)d_in[12];
    const float* fc2_w    = (const float*)d_in[13];
    const float* fc2_b    = (const float*)d_in[14];

    const int N = in_sizes[0] / 784;   // 8192

    fused_forward<<<N, TPB, 0, stream>>>(
        x, kf_w1, kf_b1, kf_w2, kf_b2, kf_fc1_w, kf_fc1_b, kf_fc2_w, kf_fc2_b,
        conv2_w, conv2_b, fc1_w, fc1_b, fc2_w, fc2_b, (float*)d_out);
}